// Round 7
// baseline (413.138 us; speedup 1.0000x reference)
//
#include <hip/hip_runtime.h>
#include <hip/hip_bf16.h>
#include <stdint.h>

#define DM 768
#define DK 64
#define NH 12
#define SQ 4096
#define BB 2

typedef __attribute__((ext_vector_type(8))) short bf16x8;
typedef __attribute__((ext_vector_type(4))) float f32x4;
typedef __attribute__((ext_vector_type(16))) float f32x16;
typedef __attribute__((ext_vector_type(4))) unsigned short u16x4;
typedef __attribute__((ext_vector_type(4))) unsigned int u32x4;
typedef unsigned short u16;
typedef unsigned int   u32;

__device__ __forceinline__ float bf2f(u16 x) {
    u32 t = ((u32)x) << 16;
    return __builtin_bit_cast(float, t);
}
__device__ __forceinline__ u16 f2bf(float f) {
    u32 u = __builtin_bit_cast(u32, f);
    u32 r = (u + 0x7fffu + ((u >> 16) & 1u)) >> 16;   // RNE
    return (u16)r;
}
// pack two positive f32 -> (bf16,bf16) via byte-select truncation (verified r6)
__device__ __forceinline__ u32 pack_trunc(float lo, float hi) {
    return __builtin_amdgcn_perm(__builtin_bit_cast(u32, hi),
                                 __builtin_bit_cast(u32, lo), 0x07060302u);
}
// async global->LDS, 16B per lane; LDS dest = wave-uniform base + lane*16
__device__ __forceinline__ void gl_lds16(const u16* g, u16* l) {
    __builtin_amdgcn_global_load_lds(
        (const __attribute__((address_space(1))) void*)g,
        (__attribute__((address_space(3))) void*)l, 16, 0, 0);
}

// ---------------------------------------------------------------------------
// GEMM: C[m,n] = (sum_k A[m,k] * W[n,k] + bias[n]) * oscale   (verified r6)
// MODE_A: 0 = f32 A, 1 = bf16 A.  MODE_OUT: 0 = bf16 row-major, 1 = f32
// row-major, 2 = bf16 V^T layout VT[((b*NH+h)*DK+d)*SQ+kv].
// ---------------------------------------------------------------------------
#define BM 128
#define BN 128
#define BKK 32
#define LDT 40

template<int MODE_A, int MODE_OUT>
__global__ __launch_bounds__(256) void gemm_bt_bias(
    const void* __restrict__ Av, const float* __restrict__ W,
    const float* __restrict__ bias, void* __restrict__ Cv, float oscale)
{
    __shared__ u16 Asm[BM * LDT];
    __shared__ u16 Bsm[BM * LDT];

    const int tid  = threadIdx.x;
    const int lane = tid & 63;
    const int w    = tid >> 6;
    const int wr   = w >> 1, wc = w & 1;
    const int l16  = lane & 15, lg = lane >> 4;

    const int ntiles = DM / BN;                 // 6
    const int mt = blockIdx.x / ntiles;
    const int nt = blockIdx.x % ntiles;
    const int m0 = mt * BM, n0 = nt * BN;

    f32x4 acc[4][4];
    #pragma unroll
    for (int mi = 0; mi < 4; ++mi)
        #pragma unroll
        for (int ni = 0; ni < 4; ++ni)
            #pragma unroll
            for (int r = 0; r < 4; ++r) acc[mi][ni][r] = 0.f;

    for (int k0 = 0; k0 < DM; k0 += BKK) {
        #pragma unroll
        for (int i = 0; i < 4; ++i) {
            int c   = tid + i * 256;
            int row = c >> 3;
            int cv  = c & 7;
            float4 b4 = *(const float4*)&W[(size_t)(n0 + row) * DM + k0 + cv * 4];
            u16x4 bb; bb.x = f2bf(b4.x); bb.y = f2bf(b4.y);
            bb.z = f2bf(b4.z); bb.w = f2bf(b4.w);
            *(u16x4*)&Bsm[row * LDT + cv * 4] = bb;
        }
        if (MODE_A == 0) {
            const float* A = (const float*)Av;
            #pragma unroll
            for (int i = 0; i < 4; ++i) {
                int c   = tid + i * 256;
                int row = c >> 3;
                int cv  = c & 7;
                float4 a4 = *(const float4*)&A[(size_t)(m0 + row) * DM + k0 + cv * 4];
                u16x4 ab; ab.x = f2bf(a4.x); ab.y = f2bf(a4.y);
                ab.z = f2bf(a4.z); ab.w = f2bf(a4.w);
                *(u16x4*)&Asm[row * LDT + cv * 4] = ab;
            }
        } else {
            const u16* A = (const u16*)Av;
            #pragma unroll
            for (int i = 0; i < 2; ++i) {
                int c   = tid + i * 256;
                int row = c >> 2;
                int col = (c & 3) * 8;
                *(uint4*)&Asm[row * LDT + col] =
                    *(const uint4*)&A[(size_t)(m0 + row) * DM + k0 + col];
            }
        }
        __syncthreads();

        bf16x8 af[4], bfr[4];
        #pragma unroll
        for (int mi = 0; mi < 4; ++mi)
            af[mi]  = *(const bf16x8*)&Asm[(wr * 64 + mi * 16 + l16) * LDT + lg * 8];
        #pragma unroll
        for (int ni = 0; ni < 4; ++ni)
            bfr[ni] = *(const bf16x8*)&Bsm[(wc * 64 + ni * 16 + l16) * LDT + lg * 8];

        #pragma unroll
        for (int mi = 0; mi < 4; ++mi)
            #pragma unroll
            for (int ni = 0; ni < 4; ++ni)
                acc[mi][ni] = __builtin_amdgcn_mfma_f32_16x16x32_bf16(
                    af[mi], bfr[ni], acc[mi][ni], 0, 0, 0);
        __syncthreads();
    }

    #pragma unroll
    for (int mi = 0; mi < 4; ++mi)
        #pragma unroll
        for (int ni = 0; ni < 4; ++ni) {
            int n = n0 + wc * 64 + ni * 16 + l16;
            float bv = bias[n];
            if (MODE_OUT == 2) {
                int hh = n >> 6, dd = n & 63;
                int mb = m0 + wr * 64 + mi * 16 + lg * 4;
                int bI = mb >> 12;
                int kv = mb & (SQ - 1);
                u16x4 pk;
                #pragma unroll
                for (int r = 0; r < 4; ++r)
                    pk[r] = f2bf((acc[mi][ni][r] + bv) * oscale);
                *(u16x4*)&((u16*)Cv)[(((size_t)bI * NH + hh) * DK + dd) * SQ + kv] = pk;
            } else {
                #pragma unroll
                for (int r = 0; r < 4; ++r) {
                    int m = m0 + wr * 64 + mi * 16 + lg * 4 + r;
                    float v = (acc[mi][ni][r] + bv) * oscale;
                    if (MODE_OUT == 1) ((float*)Cv)[(size_t)m * DM + n] = v;
                    else               ((u16*)Cv)[(size_t)m * DM + n]   = f2bf(v);
                }
            }
        }
}

// ---------------------------------------------------------------------------
// Flash attention v3: 2 waves/block, 64 q-rows per wave (2 q-groups of 32),
// double-buffered K/V LDS staged via global_load_lds with pre-swizzled
// global source (xor involution). Softmax path = verified round-6 ops.
// ---------------------------------------------------------------------------
__global__ __launch_bounds__(128) void flash_attn64(
    const u16* __restrict__ Qm, const u16* __restrict__ Km,
    const u16* __restrict__ VT, u16* __restrict__ Om)
{
    __shared__ __align__(16) u16 Ksm[2][64 * 64];
    __shared__ __align__(16) u16 Vsm[2][64 * 64];

    const int tid  = threadIdx.x;
    const int lane = tid & 63;
    const int w    = tid >> 6;          // 0..1
    const int kvL  = lane & 31;
    const int hi   = lane >> 5;

    const int qt = blockIdx.x;          // 0..31
    const int bh = blockIdx.y;          // 0..23
    const int b  = bh / NH, h = bh % NH;
    const size_t baseQ  = (size_t)b * SQ * DM + (size_t)h * DK;
    const size_t baseVT = (size_t)bh * DK * SQ;

    const int q0 = qt * 128 + w * 64 + kvL;     // q-group g adds g*32

    bf16x8 qf[2][4];
    #pragma unroll
    for (int g = 0; g < 2; ++g)
        #pragma unroll
        for (int j = 0; j < 4; ++j)
            qf[g][j] = *(const bf16x8*)
                &Qm[baseQ + (size_t)(q0 + g * 32) * DM + j * 16 + hi * 8];

    // swizzled LDS byte offsets for fragment reads (slot (2j+hi) of row kvL)
    int off[4];
    #pragma unroll
    for (int j = 0; j < 4; ++j)
        off[j] = kvL * 128 + (((2 * j + hi) ^ (kvL & 7)) << 4);

    // staging decode: issue i covers LDS bytes [(w*4+i)*1024, +1024);
    // lane covers row (w*4+i)*8 + (lane>>3), linear chunk lane&7; source
    // chunk = (lane&7) ^ (row&7) so linear DMA writes produce swizzled layout
    int srow[4], schk[4];
    #pragma unroll
    for (int i = 0; i < 4; ++i) {
        int r = (w * 4 + i) * 8 + (lane >> 3);
        srow[i] = r;
        schk[i] = (((lane & 7) ^ (r & 7)) << 3);   // element offset (x8)
    }

    f32x16 accO[2][2];
    #pragma unroll
    for (int g = 0; g < 2; ++g)
        #pragma unroll
        for (int e = 0; e < 16; ++e) { accO[g][0][e] = 0.f; accO[g][1][e] = 0.f; }
    float mrun[2] = {-1e30f, -1e30f}, lrun[2] = {0.f, 0.f};

    // prologue: stage tile 0 into buffer 0
    #pragma unroll
    for (int i = 0; i < 4; ++i) {
        gl_lds16(&Km[baseQ + (size_t)srow[i] * DM + schk[i]],
                 &Ksm[0][(w * 4 + i) * 512]);
        gl_lds16(&VT[baseVT + (size_t)srow[i] * SQ + schk[i]],
                 &Vsm[0][(w * 4 + i) * 512]);
    }
    __syncthreads();   // drains vmcnt(0): staging complete

    int cur = 0;
    for (int t = 0; t < SQ / 64; ++t) {
        // issue next tile's DMA into the other buffer (hidden under compute)
        if (t + 1 < SQ / 64) {
            int kvn = (t + 1) * 64;
            #pragma unroll
            for (int i = 0; i < 4; ++i) {
                gl_lds16(&Km[baseQ + (size_t)(kvn + srow[i]) * DM + schk[i]],
                         &Ksm[cur ^ 1][(w * 4 + i) * 512]);
                gl_lds16(&VT[baseVT + (size_t)srow[i] * SQ + kvn + schk[i]],
                         &Vsm[cur ^ 1][(w * 4 + i) * 512]);
            }
        }
        const u16* Kb = &Ksm[cur][0];
        const u16* Vb = &Vsm[cur][0];

        u32x4 wB[2][4];
        #pragma unroll
        for (int g = 0; g < 2; ++g) {
            // S^T = K . Q (log2 domain)
            f32x16 s0, s1;
            #pragma unroll
            for (int e = 0; e < 16; ++e) { s0[e] = 0.f; s1[e] = 0.f; }
            __builtin_amdgcn_s_setprio(1);
            #pragma unroll
            for (int j = 0; j < 4; ++j) {
                bf16x8 kf0 = *(const bf16x8*)((const char*)Kb + off[j]);
                bf16x8 kf1 = *(const bf16x8*)((const char*)Kb + 4096 + off[j]);
                s0 = __builtin_amdgcn_mfma_f32_32x32x16_bf16(kf0, qf[g][j], s0, 0, 0, 0);
                s1 = __builtin_amdgcn_mfma_f32_32x32x16_bf16(kf1, qf[g][j], s1, 0, 0, 0);
            }
            __builtin_amdgcn_s_setprio(0);

            // row max + cross-half
            float mx = fmaxf(s0[0], s0[1]);
            #pragma unroll
            for (int e = 2; e < 16; e += 2) mx = fmaxf(fmaxf(mx, s0[e]), s0[e + 1]);
            #pragma unroll
            for (int e = 0; e < 16; e += 2) mx = fmaxf(fmaxf(mx, s1[e]), s1[e + 1]);
            mx = fmaxf(mx, __shfl_xor(mx, 32));

            // defer-max rescale (log2 units)
            if (__any(mx > mrun[g] + 8.f)) {
                float mnew = fmaxf(mrun[g], mx);
                float al = __builtin_amdgcn_exp2f(mrun[g] - mnew);
                lrun[g] *= al;
                #pragma unroll
                for (int e = 0; e < 16; ++e) {
                    accO[g][0][e] *= al; accO[g][1][e] *= al;
                }
                mrun[g] = mnew;
            }

            // p = 2^(s-m), pack, row-sum
            u32 pb[16];
            float rs0 = 0.f, rs1 = 0.f;
            #pragma unroll
            for (int wd = 0; wd < 8; ++wd) {
                float a0 = __builtin_amdgcn_exp2f(s0[2 * wd]     - mrun[g]);
                float a1 = __builtin_amdgcn_exp2f(s0[2 * wd + 1] - mrun[g]);
                float b0 = __builtin_amdgcn_exp2f(s1[2 * wd]     - mrun[g]);
                float b1 = __builtin_amdgcn_exp2f(s1[2 * wd + 1] - mrun[g]);
                rs0 += a0 + a1;
                rs1 += b0 + b1;
                pb[wd]     = pack_trunc(a0, a1);
                pb[8 + wd] = pack_trunc(b0, b1);
            }
            {
                float rs = rs0 + rs1;
                rs += __shfl_xor(rs, 32);
                lrun[g] += rs;
            }

            // cross-half redistribution (verified round-3/6 pattern)
            u32 sw[16];
            #pragma unroll
            for (int wd = 0; wd < 16; ++wd)
                sw[wd] = (u32)__shfl_xor((int)pb[wd], 32);
            #pragma unroll
            for (int m = 0; m < 4; ++m) {
                int sb = 4 * m;
                u32x4 wds;
                wds[0] = hi ? sw[sb + 2] : pb[sb + 0];
                wds[1] = hi ? sw[sb + 3] : pb[sb + 1];
                wds[2] = hi ? pb[sb + 2] : sw[sb + 0];
                wds[3] = hi ? pb[sb + 3] : sw[sb + 1];
                wB[g][m] = wds;
            }
        }

        // O^T += V^T . P^T  (V fragments shared across both q-groups)
        __builtin_amdgcn_s_setprio(1);
        #pragma unroll
        for (int m = 0; m < 4; ++m) {
            bf16x8 v0 = *(const bf16x8*)((const char*)Vb + off[m]);
            bf16x8 v1 = *(const bf16x8*)((const char*)Vb + 4096 + off[m]);
            #pragma unroll
            for (int g = 0; g < 2; ++g) {
                bf16x8 Bp = __builtin_bit_cast(bf16x8, wB[g][m]);
                accO[g][0] = __builtin_amdgcn_mfma_f32_32x32x16_bf16(v0, Bp, accO[g][0], 0, 0, 0);
                accO[g][1] = __builtin_amdgcn_mfma_f32_32x32x16_bf16(v1, Bp, accO[g][1], 0, 0, 0);
            }
        }
        __builtin_amdgcn_s_setprio(0);

        __syncthreads();   // drains vmcnt(0): next-tile DMA done, reads done
        cur ^= 1;
    }

    #pragma unroll
    for (int g = 0; g < 2; ++g) {
        float inv = 1.f / lrun[g];
        #pragma unroll
        for (int c = 0; c < 2; ++c)
            #pragma unroll
            for (int t4 = 0; t4 < 4; ++t4) {
                int d0 = t4 * 8 + hi * 4 + c * 32;
                u16x4 pk;
                #pragma unroll
                for (int u = 0; u < 4; ++u)
                    pk[u] = f2bf(accO[g][c][t4 * 4 + u] * inv);
                *(u16x4*)&Om[baseQ + (size_t)(q0 + g * 32) * DM + d0] = pk;
            }
    }
}

// ---------------------------------------------------------------------------
extern "C" void kernel_launch(void* const* d_in, const int* in_sizes, int n_in,
                              void* d_out, int out_size, void* d_ws, size_t ws_size,
                              hipStream_t stream)
{
    const float* Q  = (const float*)d_in[0];
    const float* K  = (const float*)d_in[1];
    const float* V  = (const float*)d_in[2];
    const float* Wq = (const float*)d_in[3];
    const float* bq = (const float*)d_in[4];
    const float* Wk = (const float*)d_in[5];
    const float* bk = (const float*)d_in[6];
    const float* Wv = (const float*)d_in[7];
    const float* bv = (const float*)d_in[8];
    const float* Wo = (const float*)d_in[9];
    const float* bo = (const float*)d_in[10];
    (void)in_sizes; (void)n_in; (void)out_size; (void)ws_size;

    const size_t elems = (size_t)BB * SQ * DM;
    u16* qws  = (u16*)d_ws;
    u16* kws  = qws + elems;
    u16* vtws = kws + elems;
    u16* aws  = vtws + elems;

    dim3 gg((BB * SQ / BM) * (DM / BN));         // 384
    dim3 bt(256);

    const float qscale = 0.125f * 1.4426950408889634f;   // 1/sqrt(64) * log2(e)

    hipLaunchKernelGGL((gemm_bt_bias<0, 0>), gg, bt, 0, stream,
                       (const void*)Q, Wq, bq, (void*)qws, qscale);
    hipLaunchKernelGGL((gemm_bt_bias<0, 0>), gg, bt, 0, stream,
                       (const void*)K, Wk, bk, (void*)kws, 1.0f);
    hipLaunchKernelGGL((gemm_bt_bias<0, 2>), gg, bt, 0, stream,
                       (const void*)V, Wv, bv, (void*)vtws, 1.0f);

    dim3 ga(SQ / 128, BB * NH);                  // (32, 24)
    hipLaunchKernelGGL(flash_attn64, ga, dim3(128), 0, stream, qws, kws, vtws, aws);

    hipLaunchKernelGGL((gemm_bt_bias<1, 1>), gg, bt, 0, stream,
                       (const void*)aws, Wo, bo, d_out, 1.0f);
}

// Round 8
// 279.196 us; speedup vs baseline: 1.4797x; 1.4797x over previous
//
#include <hip/hip_runtime.h>
#include <hip/hip_bf16.h>
#include <stdint.h>

#define DM 768
#define DK 64
#define NH 12
#define SQ 4096
#define BB 2

typedef __attribute__((ext_vector_type(8))) short bf16x8;
typedef __attribute__((ext_vector_type(4))) float f32x4;
typedef __attribute__((ext_vector_type(16))) float f32x16;
typedef __attribute__((ext_vector_type(4))) unsigned short u16x4;
typedef __attribute__((ext_vector_type(4))) unsigned int u32x4;
typedef unsigned short u16;
typedef unsigned int   u32;

__device__ __forceinline__ float bf2f(u16 x) {
    u32 t = ((u32)x) << 16;
    return __builtin_bit_cast(float, t);
}
__device__ __forceinline__ u16 f2bf(float f) {
    u32 u = __builtin_bit_cast(u32, f);
    u32 r = (u + 0x7fffu + ((u >> 16) & 1u)) >> 16;   // RNE
    return (u16)r;
}
// pack two positive f32 -> (bf16,bf16) via byte-select truncation (verified r6)
__device__ __forceinline__ u32 pack_trunc(float lo, float hi) {
    return __builtin_amdgcn_perm(__builtin_bit_cast(u32, hi),
                                 __builtin_bit_cast(u32, lo), 0x07060302u);
}
// async global->LDS, 16B per lane; LDS dest = wave-uniform base + lane*16
__device__ __forceinline__ void gl_lds16(const u16* g, u16* l) {
    __builtin_amdgcn_global_load_lds(
        (const __attribute__((address_space(1))) void*)g,
        (__attribute__((address_space(3))) void*)l, 16, 0, 0);
}

// ---------------------------------------------------------------------------
// GEMM: C[m,n] = (sum_k A[m,k] * W[n,k] + bias[n]) * oscale   (verified r6)
// MODE_A: 0 = f32 A, 1 = bf16 A.  MODE_OUT: 0 = bf16 row-major, 1 = f32
// row-major, 2 = bf16 V^T layout VT[((b*NH+h)*DK+d)*SQ+kv].
// ---------------------------------------------------------------------------
#define BM 128
#define BN 128
#define BKK 32
#define LDT 40

template<int MODE_A, int MODE_OUT>
__global__ __launch_bounds__(256) void gemm_bt_bias(
    const void* __restrict__ Av, const float* __restrict__ W,
    const float* __restrict__ bias, void* __restrict__ Cv, float oscale)
{
    __shared__ u16 Asm[BM * LDT];
    __shared__ u16 Bsm[BM * LDT];

    const int tid  = threadIdx.x;
    const int lane = tid & 63;
    const int w    = tid >> 6;
    const int wr   = w >> 1, wc = w & 1;
    const int l16  = lane & 15, lg = lane >> 4;

    const int ntiles = DM / BN;                 // 6
    const int mt = blockIdx.x / ntiles;
    const int nt = blockIdx.x % ntiles;
    const int m0 = mt * BM, n0 = nt * BN;

    f32x4 acc[4][4];
    #pragma unroll
    for (int mi = 0; mi < 4; ++mi)
        #pragma unroll
        for (int ni = 0; ni < 4; ++ni)
            #pragma unroll
            for (int r = 0; r < 4; ++r) acc[mi][ni][r] = 0.f;

    for (int k0 = 0; k0 < DM; k0 += BKK) {
        #pragma unroll
        for (int i = 0; i < 4; ++i) {
            int c   = tid + i * 256;
            int row = c >> 3;
            int cv  = c & 7;
            float4 b4 = *(const float4*)&W[(size_t)(n0 + row) * DM + k0 + cv * 4];
            u16x4 bb; bb.x = f2bf(b4.x); bb.y = f2bf(b4.y);
            bb.z = f2bf(b4.z); bb.w = f2bf(b4.w);
            *(u16x4*)&Bsm[row * LDT + cv * 4] = bb;
        }
        if (MODE_A == 0) {
            const float* A = (const float*)Av;
            #pragma unroll
            for (int i = 0; i < 4; ++i) {
                int c   = tid + i * 256;
                int row = c >> 3;
                int cv  = c & 7;
                float4 a4 = *(const float4*)&A[(size_t)(m0 + row) * DM + k0 + cv * 4];
                u16x4 ab; ab.x = f2bf(a4.x); ab.y = f2bf(a4.y);
                ab.z = f2bf(a4.z); ab.w = f2bf(a4.w);
                *(u16x4*)&Asm[row * LDT + cv * 4] = ab;
            }
        } else {
            const u16* A = (const u16*)Av;
            #pragma unroll
            for (int i = 0; i < 2; ++i) {
                int c   = tid + i * 256;
                int row = c >> 2;
                int col = (c & 3) * 8;
                *(uint4*)&Asm[row * LDT + col] =
                    *(const uint4*)&A[(size_t)(m0 + row) * DM + k0 + col];
            }
        }
        __syncthreads();

        bf16x8 af[4], bfr[4];
        #pragma unroll
        for (int mi = 0; mi < 4; ++mi)
            af[mi]  = *(const bf16x8*)&Asm[(wr * 64 + mi * 16 + l16) * LDT + lg * 8];
        #pragma unroll
        for (int ni = 0; ni < 4; ++ni)
            bfr[ni] = *(const bf16x8*)&Bsm[(wc * 64 + ni * 16 + l16) * LDT + lg * 8];

        #pragma unroll
        for (int mi = 0; mi < 4; ++mi)
            #pragma unroll
            for (int ni = 0; ni < 4; ++ni)
                acc[mi][ni] = __builtin_amdgcn_mfma_f32_16x16x32_bf16(
                    af[mi], bfr[ni], acc[mi][ni], 0, 0, 0);
        __syncthreads();
    }

    #pragma unroll
    for (int mi = 0; mi < 4; ++mi)
        #pragma unroll
        for (int ni = 0; ni < 4; ++ni) {
            int n = n0 + wc * 64 + ni * 16 + l16;
            float bv = bias[n];
            if (MODE_OUT == 2) {
                int hh = n >> 6, dd = n & 63;
                int mb = m0 + wr * 64 + mi * 16 + lg * 4;
                int bI = mb >> 12;
                int kv = mb & (SQ - 1);
                u16x4 pk;
                #pragma unroll
                for (int r = 0; r < 4; ++r)
                    pk[r] = f2bf((acc[mi][ni][r] + bv) * oscale);
                *(u16x4*)&((u16*)Cv)[(((size_t)bI * NH + hh) * DK + dd) * SQ + kv] = pk;
            } else {
                #pragma unroll
                for (int r = 0; r < 4; ++r) {
                    int m = m0 + wr * 64 + mi * 16 + lg * 4 + r;
                    float v = (acc[mi][ni][r] + bv) * oscale;
                    if (MODE_OUT == 1) ((float*)Cv)[(size_t)m * DM + n] = v;
                    else               ((u16*)Cv)[(size_t)m * DM + n]   = f2bf(v);
                }
            }
        }
}

// ---------------------------------------------------------------------------
// Flash attention v4: in-block KV-split. 8 waves (512 thr); wave w handles
// q-group (w&3) and kv-half (w>>2): even 64-kv tiles for half 0, odd for
// half 1. Per-wave inner loop = verified round-6 code. DMA staging with
// pre-swizzled source (verified r7). Final cross-half online-softmax merge
// in LDS (exact).
// ---------------------------------------------------------------------------
__global__ __launch_bounds__(512) void flash_attn_ks(
    const u16* __restrict__ Qm, const u16* __restrict__ Km,
    const u16* __restrict__ VT, u16* __restrict__ Om)
{
    // union: stage K0|V0|K1|V1 (4x8KB=32KB)  /  merge O[4][32][68]f32 + ml
    __shared__ __align__(16) char ldsbuf[36864];

    const int tid  = threadIdx.x;
    const int lane = tid & 63;
    const int w    = tid >> 6;          // 0..7
    const int qg   = w & 3;
    const int half = w >> 2;
    const int kvL  = lane & 31;
    const int hi   = lane >> 5;

    const int qt = blockIdx.x;          // 0..31
    const int bh = blockIdx.y;          // 0..23
    const int b  = bh / NH, h = bh % NH;
    const size_t baseQ  = (size_t)b * SQ * DM + (size_t)h * DK;
    const size_t baseVT = (size_t)bh * DK * SQ;

    const int q = qt * 128 + qg * 32 + kvL;

    bf16x8 qf[4];
    #pragma unroll
    for (int j = 0; j < 4; ++j)
        qf[j] = *(const bf16x8*)&Qm[baseQ + (size_t)q * DM + j * 16 + hi * 8];

    // swizzled LDS byte offsets for fragment reads (slot (2j+hi) of row kvL)
    int off[4];
    #pragma unroll
    for (int j = 0; j < 4; ++j)
        off[j] = kvL * 128 + (((2 * j + hi) ^ (kvL & 7)) << 4);

    // staging decode (verified r7): wave stages its own half's K+V tile.
    // issue i covers local rows (qg*2+i)*8 + (lane>>3); source chunk
    // pre-swizzled so linear DMA lands swizzled.
    int srow[2], schk[2];
    #pragma unroll
    for (int i = 0; i < 2; ++i) {
        int r = (qg * 2 + i) * 8 + (lane >> 3);
        srow[i] = r;
        schk[i] = (((lane & 7) ^ (r & 7)) << 3);
    }
    u16* KL = (u16*)(ldsbuf + half * 16384);
    u16* VL = (u16*)(ldsbuf + half * 16384 + 8192);

    f32x16 accO[2];
    #pragma unroll
    for (int e = 0; e < 16; ++e) { accO[0][e] = 0.f; accO[1][e] = 0.f; }
    float mrun = -1e30f, lrun = 0.f;

    for (int t = 0; t < SQ / 128; ++t) {
        const int kv0 = t * 128 + half * 64;
        #pragma unroll
        for (int i = 0; i < 2; ++i) {
            gl_lds16(&Km[baseQ + (size_t)(kv0 + srow[i]) * DM + schk[i]],
                     KL + (qg * 2 + i) * 512);
            gl_lds16(&VT[baseVT + (size_t)srow[i] * SQ + kv0 + schk[i]],
                     VL + (qg * 2 + i) * 512);
        }
        __syncthreads();   // drains vmcnt(0): both halves staged

        // ---- verified round-6 inner compute ----
        f32x16 s0, s1;
        #pragma unroll
        for (int e = 0; e < 16; ++e) { s0[e] = 0.f; s1[e] = 0.f; }
        __builtin_amdgcn_s_setprio(1);
        #pragma unroll
        for (int j = 0; j < 4; ++j) {
            bf16x8 kf0 = *(const bf16x8*)((const char*)KL + off[j]);
            bf16x8 kf1 = *(const bf16x8*)((const char*)KL + 4096 + off[j]);
            s0 = __builtin_amdgcn_mfma_f32_32x32x16_bf16(kf0, qf[j], s0, 0, 0, 0);
            s1 = __builtin_amdgcn_mfma_f32_32x32x16_bf16(kf1, qf[j], s1, 0, 0, 0);
        }
        __builtin_amdgcn_s_setprio(0);

        float mx = fmaxf(s0[0], s0[1]);
        #pragma unroll
        for (int e = 2; e < 16; e += 2) mx = fmaxf(fmaxf(mx, s0[e]), s0[e + 1]);
        #pragma unroll
        for (int e = 0; e < 16; e += 2) mx = fmaxf(fmaxf(mx, s1[e]), s1[e + 1]);
        mx = fmaxf(mx, __shfl_xor(mx, 32));

        if (__any(mx > mrun + 8.f)) {
            float mnew = fmaxf(mrun, mx);
            float al = __builtin_amdgcn_exp2f(mrun - mnew);
            lrun *= al;
            #pragma unroll
            for (int e = 0; e < 16; ++e) { accO[0][e] *= al; accO[1][e] *= al; }
            mrun = mnew;
        }

        u32 pb[16];
        float rs0 = 0.f, rs1 = 0.f;
        #pragma unroll
        for (int wd = 0; wd < 8; ++wd) {
            float a0 = __builtin_amdgcn_exp2f(s0[2 * wd]     - mrun);
            float a1 = __builtin_amdgcn_exp2f(s0[2 * wd + 1] - mrun);
            float b0 = __builtin_amdgcn_exp2f(s1[2 * wd]     - mrun);
            float b1 = __builtin_amdgcn_exp2f(s1[2 * wd + 1] - mrun);
            rs0 += a0 + a1;
            rs1 += b0 + b1;
            pb[wd]     = pack_trunc(a0, a1);
            pb[8 + wd] = pack_trunc(b0, b1);
        }
        {
            float rs = rs0 + rs1;
            rs += __shfl_xor(rs, 32);
            lrun += rs;
        }

        u32 sw[16];
        #pragma unroll
        for (int wd = 0; wd < 16; ++wd)
            sw[wd] = (u32)__shfl_xor((int)pb[wd], 32);

        __builtin_amdgcn_s_setprio(1);
        #pragma unroll
        for (int m = 0; m < 4; ++m) {
            int sb = 4 * m;
            u32x4 wds;
            wds[0] = hi ? sw[sb + 2] : pb[sb + 0];
            wds[1] = hi ? sw[sb + 3] : pb[sb + 1];
            wds[2] = hi ? pb[sb + 2] : sw[sb + 0];
            wds[3] = hi ? pb[sb + 3] : sw[sb + 1];
            bf16x8 Bp = __builtin_bit_cast(bf16x8, wds);
            bf16x8 v0 = *(const bf16x8*)((const char*)VL + off[m]);
            bf16x8 v1 = *(const bf16x8*)((const char*)VL + 4096 + off[m]);
            accO[0] = __builtin_amdgcn_mfma_f32_32x32x16_bf16(v0, Bp, accO[0], 0, 0, 0);
            accO[1] = __builtin_amdgcn_mfma_f32_32x32x16_bf16(v1, Bp, accO[1], 0, 0, 0);
        }
        __builtin_amdgcn_s_setprio(0);
        __syncthreads();   // compute done before next stage overwrites
    }

    // ---- cross-half merge (exact online-softmax combine) ----
    float* mo = (float*)ldsbuf;                    // [qg][q=32][68] f32
    float* ml = (float*)(ldsbuf + 34816);          // [qg][q=32][2]  f32
    const int rowi = (qg * 32 + kvL);

    if (half == 1) {
        float* row = mo + rowi * 68;
        #pragma unroll
        for (int c = 0; c < 2; ++c)
            #pragma unroll
            for (int e = 0; e < 16; ++e)
                row[(e >> 2) * 8 + (e & 3) + hi * 4 + c * 32] = accO[c][e];
        if (hi == 0) { ml[rowi * 2] = mrun; ml[rowi * 2 + 1] = lrun; }
    }
    __syncthreads();
    if (half == 0) {
        float* row = mo + rowi * 68;
        float mb2 = ml[rowi * 2], lb2 = ml[rowi * 2 + 1];
        float mstar = fmaxf(mrun, mb2);
        float fa = __builtin_amdgcn_exp2f(mrun - mstar);
        float fb = __builtin_amdgcn_exp2f(mb2 - mstar);
        float inv = 1.f / (lrun * fa + lb2 * fb);
        #pragma unroll
        for (int c = 0; c < 2; ++c)
            #pragma unroll
            for (int t4 = 0; t4 < 4; ++t4) {
                int d0 = t4 * 8 + hi * 4 + c * 32;
                u16x4 pk;
                #pragma unroll
                for (int u = 0; u < 4; ++u) {
                    float val = (accO[c][t4 * 4 + u] * fa + row[d0 + u] * fb) * inv;
                    pk[u] = f2bf(val);
                }
                *(u16x4*)&Om[baseQ + (size_t)q * DM + d0] = pk;
            }
    }
}

// ---------------------------------------------------------------------------
extern "C" void kernel_launch(void* const* d_in, const int* in_sizes, int n_in,
                              void* d_out, int out_size, void* d_ws, size_t ws_size,
                              hipStream_t stream)
{
    const float* Q  = (const float*)d_in[0];
    const float* K  = (const float*)d_in[1];
    const float* V  = (const float*)d_in[2];
    const float* Wq = (const float*)d_in[3];
    const float* bq = (const float*)d_in[4];
    const float* Wk = (const float*)d_in[5];
    const float* bk = (const float*)d_in[6];
    const float* Wv = (const float*)d_in[7];
    const float* bv = (const float*)d_in[8];
    const float* Wo = (const float*)d_in[9];
    const float* bo = (const float*)d_in[10];
    (void)in_sizes; (void)n_in; (void)out_size; (void)ws_size;

    const size_t elems = (size_t)BB * SQ * DM;
    u16* qws  = (u16*)d_ws;
    u16* kws  = qws + elems;
    u16* vtws = kws + elems;
    u16* aws  = vtws + elems;

    dim3 gg((BB * SQ / BM) * (DM / BN));         // 384
    dim3 bt(256);

    const float qscale = 0.125f * 1.4426950408889634f;   // 1/sqrt(64) * log2(e)

    hipLaunchKernelGGL((gemm_bt_bias<0, 0>), gg, bt, 0, stream,
                       (const void*)Q, Wq, bq, (void*)qws, qscale);
    hipLaunchKernelGGL((gemm_bt_bias<0, 0>), gg, bt, 0, stream,
                       (const void*)K, Wk, bk, (void*)kws, 1.0f);
    hipLaunchKernelGGL((gemm_bt_bias<0, 2>), gg, bt, 0, stream,
                       (const void*)V, Wv, bv, (void*)vtws, 1.0f);

    dim3 ga(SQ / 128, BB * NH);                  // (32, 24)
    hipLaunchKernelGGL(flash_attn_ks, ga, dim3(512), 0, stream, qws, kws, vtws, aws);

    hipLaunchKernelGGL((gemm_bt_bias<1, 1>), gg, bt, 0, stream,
                       (const void*)aws, Wo, bo, d_out, 1.0f);
}